// Round 4
// baseline (699.467 us; speedup 1.0000x reference)
//
#include <hip/hip_runtime.h>
#include <stdint.h>

#define N_HEADS   32
#define N_KV      8
#define HEAD_DIM  128
#define HIDDEN_DIM 4096
#define BSZ       2
#define SEQ       2048
#define TOT_HEADS 48
#define QKV_DIM   6144   // TOT_HEADS * HEAD_DIM
#define ROWS      4096   // BSZ * SEQ
#define ROPE_HEADS 40    // Q + K heads (V not rope'd)

typedef __attribute__((ext_vector_type(4)))  float f32x4;
typedef __attribute__((ext_vector_type(16))) float f32x16;
typedef __attribute__((ext_vector_type(8)))  short bf16x8;
typedef unsigned short u16;
typedef unsigned int   u32;

#define AS1 __attribute__((address_space(1)))
#define AS3 __attribute__((address_space(3)))

static __device__ __forceinline__ float bf16f(u16 u) { return __uint_as_float(((u32)u) << 16); }
static __device__ __forceinline__ u16 f2bf(float f) {
  u32 x = __float_as_uint(f);
  x += 0x7fffu + ((x >> 16) & 1u);   // round-to-nearest-even
  return (u16)(x >> 16);
}
static __device__ __forceinline__ u32 cvt_pk_bf16(float lo, float hi) {
  u32 r;
  asm("v_cvt_pk_bf16_f32 %0, %1, %2" : "=v"(r) : "v"(lo), "v"(hi));
  return r;
}
static __device__ __forceinline__ bf16x8 mk8(u32 a, u32 b, u32 c, u32 d) {
  union { u32 u[4]; bf16x8 v; } x;
  x.u[0] = a; x.u[1] = b; x.u[2] = c; x.u[3] = d;
  return x.v;
}

// ---------------- cast f32 -> bf16 (vectorized) ----------------
__global__ void cast_f32_bf16_k(const float4* __restrict__ in, ushort4* __restrict__ out, int n4) {
  int i = blockIdx.x * blockDim.x + threadIdx.x;
  const int stride = gridDim.x * blockDim.x;
  for (; i < n4; i += stride) {
    float4 v = in[i];
    ushort4 o;
    o.x = f2bf(v.x); o.y = f2bf(v.y); o.z = f2bf(v.z); o.w = f2bf(v.w);
    out[i] = o;
  }
}

// ---------------- RoPE cos/sin tables (S x 64, half-dim) ----------------
__global__ void rope_tables_k(float* __restrict__ ctab, float* __restrict__ stab) {
  int t = blockIdx.x * blockDim.x + threadIdx.x;
  if (t >= SEQ * 64) return;
  int s = t >> 6, i = t & 63;
  float inv = powf(10000.0f, -(float)i / 64.0f);
  float ang = (float)s * inv;
  float sv, cv;
  sincosf(ang, &sv, &cv);
  ctab[t] = cv; stab[t] = sv;
}

// ---------------- bf16 GEMM: C[M,N] = A[M,K] * B[N,K]^T ----------------
// 128x128 tile, BK=64, 4 waves (2x2), each wave 64x64 via 4x4 mfma_16x16x32 frags.
// LDS logical layout: slot(row, cs) holds global chunk c = cs ^ (row&7).
// Staging via global_load_lds (linear LDS dest, swizzle pre-applied to per-lane
// GLOBAL source address — same involution as the swizzled ds_read).
template<int F32OUT>
__global__ __launch_bounds__(256, 2)
void gemm_bt_k(const u16* __restrict__ A, const u16* __restrict__ Bw,
               void* __restrict__ C, int M, int N, int K)
{
  __shared__ uint4 smA[1024];
  __shared__ uint4 smB[1024];
  const int tid = threadIdx.x;
  const int nbx = N >> 7;
  const int bm = (blockIdx.x / nbx) << 7;
  const int bn = (blockIdx.x % nbx) << 7;
  const int lane = tid & 63;
  const int wave = tid >> 6;
  const int wm = (wave >> 1) << 6;
  const int wn = (wave & 1) << 6;
  const int fr = lane & 15;   // fragment row/col within 16
  const int fq = lane >> 4;   // 0..3

  f32x4 acc[4][4];
#pragma unroll
  for (int i = 0; i < 4; ++i)
#pragma unroll
    for (int j = 0; j < 4; ++j)
      acc[i][j] = {0.f, 0.f, 0.f, 0.f};

  const int gl_r = lane >> 3;                  // row-within-8 for this lane
  const int gl_c = (lane & 7) ^ gl_r;          // pre-swizzled global chunk

  for (int k0 = 0; k0 < K; k0 += 64) {
#pragma unroll
    for (int i = 0; i < 4; ++i) {
      const int rbase = (wave << 5) + (i << 3);      // wave-uniform row base
      const int row = rbase + gl_r;
      const u16* gA = A  + (size_t)(bm + row) * K + k0 + (gl_c << 3);
      const u16* gB = Bw + (size_t)(bn + row) * K + k0 + (gl_c << 3);
      __builtin_amdgcn_global_load_lds((const AS1 u32*)gA, (AS3 u32*)&smA[rbase << 3], 16, 0, 0);
      __builtin_amdgcn_global_load_lds((const AS1 u32*)gB, (AS3 u32*)&smB[rbase << 3], 16, 0, 0);
    }
    __syncthreads();
#pragma unroll
    for (int kk = 0; kk < 2; ++kk) {
      bf16x8 af[4], bfr[4];
      const int cc = (kk << 2) + fq;
#pragma unroll
      for (int m = 0; m < 4; ++m) {
        const int row = wm + (m << 4) + fr;
        af[m] = *reinterpret_cast<const bf16x8*>(&smA[(row << 3) + (cc ^ (row & 7))]);
      }
#pragma unroll
      for (int n = 0; n < 4; ++n) {
        const int row = wn + (n << 4) + fr;
        bfr[n] = *reinterpret_cast<const bf16x8*>(&smB[(row << 3) + (cc ^ (row & 7))]);
      }
#pragma unroll
      for (int m = 0; m < 4; ++m)
#pragma unroll
        for (int n = 0; n < 4; ++n)
          acc[m][n] = __builtin_amdgcn_mfma_f32_16x16x32_bf16(af[m], bfr[n], acc[m][n], 0, 0, 0);
    }
    __syncthreads();
  }

  // epilogue: D[row][col], row = fq*4+i (+m*16), col = fr (+n*16)
  const int col0 = bn + wn + fr;
#pragma unroll
  for (int m = 0; m < 4; ++m) {
#pragma unroll
    for (int i = 0; i < 4; ++i) {
      const int row = bm + wm + (m << 4) + (fq << 2) + i;
      if (F32OUT) {
        float* rp = reinterpret_cast<float*>(C) + (size_t)row * N + col0;
#pragma unroll
        for (int n = 0; n < 4; ++n) rp[n << 4] = acc[m][n][i];
      } else {
        u16* rp = reinterpret_cast<u16*>(C) + (size_t)row * N + col0;
#pragma unroll
        for (int n = 0; n < 4; ++n) rp[n << 4] = f2bf(acc[m][n][i]);
      }
    }
  }
}

// ---------------- RoPE + scatter Q,K heads -> Q(B,H,S,D) K(B,KV,S,D) ----------------
// Q heads are pre-scaled by 1/sqrt(128)*log2(e) so attention scores come out of
// the QK^T MFMA already in log2 domain.
__global__ void rope_scatter_k(const u16* __restrict__ QKV,
                               const float* __restrict__ ctab, const float* __restrict__ stab,
                               u16* __restrict__ Qo, u16* __restrict__ Ko)
{
  const int t = blockIdx.x * blockDim.x + threadIdx.x;  // ROWS*40*64 threads
  const int d = t & 63;
  const int hh = (t >> 6) % ROPE_HEADS;
  const int row = t / (64 * ROPE_HEADS);
  const int b = row >> 11, sq = row & (SEQ - 1);
  const u16* src = QKV + (size_t)row * QKV_DIM + hh * HEAD_DIM;
  const float x1 = bf16f(src[d]);
  const float x2 = bf16f(src[d + 64]);
  const float c = ctab[(sq << 6) + d], sn = stab[(sq << 6) + d];
  float y1 = x1 * c - x2 * sn;
  float y2 = x2 * c + x1 * sn;
  u16* dst;
  if (hh < N_HEADS) {
    const float SC2 = 0.1275170747f;   // (1/sqrt(128)) * log2(e)
    y1 *= SC2; y2 *= SC2;
    dst = Qo + ((size_t)(b * N_HEADS + hh) * SEQ + sq) * HEAD_DIM;
  } else {
    dst = Ko + ((size_t)(b * N_KV + (hh - N_HEADS)) * SEQ + sq) * HEAD_DIM;
  }
  dst[d] = f2bf(y1);
  dst[d + 64] = f2bf(y2);
}

// ---------------- V transpose: QKV cols [5120,6144) -> Vt[b][kv][d][s] ----------------
// 64x64 u16 tile = 4096 elems; 256 threads x 8 elems => TWO passes each phase.
__global__ __launch_bounds__(256)
void vtrans_k(const u16* __restrict__ QKV, u16* __restrict__ Vt)
{
  __shared__ u16 tile[64][72];
  const int idx = blockIdx.x;           // dt(1) | st(5) | kv(3) | b(1)
  const int dt = idx & 1;
  const int st = (idx >> 1) & 31;
  const int kv = (idx >> 6) & 7;
  const int b  = idx >> 9;
  const int tid = threadIdx.x;
  const int s0 = st << 6, d0 = dt << 6;
  const int rl = tid >> 3, cc8 = (tid & 7) << 3;
#pragma unroll
  for (int p = 0; p < 2; ++p) {
    const int sl = rl + (p << 5);
    const u16* src = QKV + (size_t)(b * SEQ + s0 + sl) * QKV_DIM
                   + (N_HEADS + N_KV + kv) * HEAD_DIM + d0 + cc8;
    *reinterpret_cast<uint4*>(&tile[sl][cc8]) = *reinterpret_cast<const uint4*>(src);
  }
  __syncthreads();
#pragma unroll
  for (int p = 0; p < 2; ++p) {
    const int dl = rl + (p << 5);
    u16 tmp[8];
#pragma unroll
    for (int k2 = 0; k2 < 8; ++k2) tmp[k2] = tile[cc8 + k2][dl];
    u16* dst = Vt + ((size_t)(b * N_KV + kv) * HEAD_DIM + d0 + dl) * SEQ + s0 + cc8;
    *reinterpret_cast<uint4*>(dst) = *reinterpret_cast<const uint4*>(tmp);
  }
}

// ---------------- MFMA flash attention (causal GQA) ----------------
// ONE WAVE per (b, head, 32-row q-tile). Grid 4096, block 64: fine-grained
// scheduling (33:1 triangular imbalance packs well), kvh = idx&7 pins each KV
// head's ~1MB K+V to one XCD's L2. Uniform 32-key subtile loop, V loads issued
// at loop top (latency hidden under QK+softmax). Q pre-scaled to log2 domain.
// Swapped QK^T: T = mfma(K, Q) -> lane holds scores of q-row (lane&31).
// PV output D-rows are q = (r&3)+8*(r>>2)+4*(lane>>5): stats redistributed
// per-register via __shfl when applied to O.
__global__ __launch_bounds__(64)
void attn_mfma_k(const u16* __restrict__ Q, const u16* __restrict__ K,
                 const u16* __restrict__ Vt, u16* __restrict__ Out)
{
  const int lane = threadIdx.x;
  const int idx  = blockIdx.x;                    // qrev(6) | b(1) | h2(2) | kvh(3)
  const int kvh  = idx & 7;
  const int h2   = (idx >> 3) & 3;
  const int b    = (idx >> 5) & 1;
  const int qi   = 63 - (idx >> 6);               // heaviest q-tiles first
  const int q0   = qi << 5;
  const int h    = (kvh << 2) + h2;

  const int ql = lane & 31;
  const int hh = lane >> 5;
  const int q  = q0 + ql;

  const u16* Qb = Q  + ((size_t)(b * N_HEADS + h) * SEQ + q0) * HEAD_DIM;
  const u16* Kb = K  + ((size_t)(b * N_KV + kvh) * SEQ) * HEAD_DIM;
  const u16* Vb = Vt + ((size_t)(b * N_KV + kvh) * HEAD_DIM) * SEQ;

  // Q B-frags: lane holds Q[q0+ql][16f + 8*hh + j]  (already log2-scaled)
  bf16x8 qf[8];
#pragma unroll
  for (int f = 0; f < 8; ++f)
    qf[f] = *reinterpret_cast<const bf16x8*>(Qb + (size_t)ql * HEAD_DIM + 16 * f + 8 * hh);

  f32x16 o[4];
#pragma unroll
  for (int dblk = 0; dblk < 4; ++dblk)
#pragma unroll
    for (int r = 0; r < 16; ++r) o[dblk][r] = 0.f;
  float m2 = -1e30f, lsum = 0.f;

  const int nsub = (q0 >> 5) + 1;

  for (int s = 0; s < nsub; ++s) {
    const int ks = s << 5;

    // ---- V loads first (independent of QK result -> latency hidden) ----
    const u16* Vr = Vb + (size_t)ql * SEQ + ks + 8 * hh;
    bf16x8 va[4], vb[4];
#pragma unroll
    for (int dblk = 0; dblk < 4; ++dblk) {
      const u16* vp = Vr + (size_t)(dblk * 32) * SEQ;
      va[dblk] = *reinterpret_cast<const bf16x8*>(vp);
      vb[dblk] = *reinterpret_cast<const bf16x8*>(vp + 16);
    }

    // ---- QK^T (scores arrive in log2 domain) ----
    f32x16 T;
#pragma unroll
    for (int r = 0; r < 16; ++r) T[r] = 0.f;
    {
      const u16* Kr = Kb + (size_t)(ks + ql) * HEAD_DIM + 8 * hh;
      __builtin_amdgcn_s_setprio(1);
#pragma unroll
      for (int f = 0; f < 8; ++f) {
        const bf16x8 kf = *reinterpret_cast<const bf16x8*>(Kr + 16 * f);
        T = __builtin_amdgcn_mfma_f32_32x32x16_bf16(kf, qf[f], T, 0, 0, 0);
      }
      __builtin_amdgcn_s_setprio(0);
    }

    // ---- causal mask (tail subtile only) + tile max ----
    if (s == nsub - 1) {
#pragma unroll
      for (int r = 0; r < 16; ++r) {
        const int krow = ks + (r & 3) + ((r >> 2) << 3) + (hh << 2);
        if (krow > q) T[r] = -1e30f;
      }
    }
    float mt = T[0];
#pragma unroll
    for (int r = 1; r < 16; ++r) mt = fmaxf(mt, T[r]);
    mt = fmaxf(mt, __shfl_xor(mt, 32));

    // ---- defer-max rescale (THR = 8 in log2 domain) ----
    if (__any(mt > m2 + 8.f)) {
      const float mnew = fmaxf(m2, mt);
      const float resc = exp2f(m2 - mnew);
      lsum *= resc;
#pragma unroll
      for (int r = 0; r < 16; ++r) {
        const int qr = (r & 3) + ((r >> 2) << 3) + (hh << 2);
        const float rr = __shfl(resc, qr);
#pragma unroll
        for (int dblk = 0; dblk < 4; ++dblk) o[dblk][r] *= rr;
      }
      m2 = mnew;
    }

    // ---- exp2 + row sum ----
    float ps = 0.f;
#pragma unroll
    for (int r = 0; r < 16; ++r) { const float p = exp2f(T[r] - m2); T[r] = p; ps += p; }
    ps += __shfl_xor(ps, 32);
    lsum += ps;

    // ---- pack P -> bf16 A-frags (cvt_pk + half-swap) ----
    u32 pk[8], sw[8];
#pragma unroll
    for (int i = 0; i < 8; ++i) {
      pk[i] = cvt_pk_bf16(T[2 * i], T[2 * i + 1]);
      sw[i] = (u32)__shfl_xor((int)pk[i], 32);
    }
    const bf16x8 a0 = hh ? mk8(sw[2], sw[3], pk[2], pk[3])
                         : mk8(pk[0], pk[1], sw[0], sw[1]);
    const bf16x8 a1 = hh ? mk8(sw[6], sw[7], pk[6], pk[7])
                         : mk8(pk[4], pk[5], sw[4], sw[5]);

    // ---- PV ----
    __builtin_amdgcn_s_setprio(1);
#pragma unroll
    for (int dblk = 0; dblk < 4; ++dblk) {
      o[dblk] = __builtin_amdgcn_mfma_f32_32x32x16_bf16(a0, va[dblk], o[dblk], 0, 0, 0);
      o[dblk] = __builtin_amdgcn_mfma_f32_32x32x16_bf16(a1, vb[dblk], o[dblk], 0, 0, 0);
    }
    __builtin_amdgcn_s_setprio(0);
  }

  // ---- write out: row q0+qr, col h*128 + dblk*32 + ql; normalize with lsum[qr] ----
  u16* Ob = Out + (size_t)(b * SEQ + q0) * HIDDEN_DIM + h * HEAD_DIM + ql;
#pragma unroll
  for (int r = 0; r < 16; ++r) {
    const int qr = (r & 3) + ((r >> 2) << 3) + (hh << 2);
    const float il = 1.0f / __shfl(lsum, qr);
    u16* rp = Ob + (size_t)qr * HIDDEN_DIM;
#pragma unroll
    for (int dblk = 0; dblk < 4; ++dblk)
      rp[dblk * 32] = f2bf(o[dblk][r] * il);
  }
}

// ---------------- launch ----------------
extern "C" void kernel_launch(void* const* d_in, const int* in_sizes, int n_in,
                              void* d_out, int out_size, void* d_ws, size_t ws_size,
                              hipStream_t stream)
{
  const float* hs   = (const float*)d_in[0];
  const float* wqkv = (const float*)d_in[1];
  const float* wo   = (const float*)d_in[2];
  float* out = (float*)d_out;
  char* ws = (char*)d_ws;
  size_t off = 0;
  auto alloc = [&](size_t bytes) -> void* {
    void* p = ws + off;
    off += (bytes + 255) & ~(size_t)255;
    return p;
  };
  u16* Xbf    = (u16*)alloc((size_t)ROWS * HIDDEN_DIM * 2);
  u16* Wqkvbf = (u16*)alloc((size_t)QKV_DIM * HIDDEN_DIM * 2);
  u16* Wobf   = (u16*)alloc((size_t)HIDDEN_DIM * HIDDEN_DIM * 2);
  u16* QKVbf  = (u16*)alloc((size_t)ROWS * QKV_DIM * 2);
  u16* Qbf    = (u16*)alloc((size_t)BSZ * N_HEADS * SEQ * HEAD_DIM * 2);
  u16* Kbf    = (u16*)alloc((size_t)BSZ * N_KV * SEQ * HEAD_DIM * 2);
  u16* Vtbf   = (u16*)alloc((size_t)BSZ * N_KV * SEQ * HEAD_DIM * 2);
  float* ctab = (float*)alloc((size_t)SEQ * 64 * 4);
  float* stab = (float*)alloc((size_t)SEQ * 64 * 4);
  u16* AOut   = (u16*)alloc((size_t)ROWS * HIDDEN_DIM * 2);
  if (off > ws_size) return;

  cast_f32_bf16_k<<<2048, 256, 0, stream>>>((const float4*)hs,   (ushort4*)Xbf,    ROWS * HIDDEN_DIM / 4);
  cast_f32_bf16_k<<<2048, 256, 0, stream>>>((const float4*)wqkv, (ushort4*)Wqkvbf, QKV_DIM * HIDDEN_DIM / 4);
  cast_f32_bf16_k<<<2048, 256, 0, stream>>>((const float4*)wo,   (ushort4*)Wobf,   HIDDEN_DIM * HIDDEN_DIM / 4);
  rope_tables_k<<<(SEQ * 64) / 256, 256, 0, stream>>>(ctab, stab);

  gemm_bt_k<0><<<(ROWS / 128) * (QKV_DIM / 128), 256, 0, stream>>>(Xbf, Wqkvbf, (void*)QKVbf,
                                                                   ROWS, QKV_DIM, HIDDEN_DIM);
  rope_scatter_k<<<ROWS * ROPE_HEADS * 64 / 256, 256, 0, stream>>>(QKVbf, ctab, stab, Qbf, Kbf);
  vtrans_k<<<BSZ * N_KV * (SEQ / 64) * (HEAD_DIM / 64), 256, 0, stream>>>(QKVbf, Vtbf);
  attn_mfma_k<<<BSZ * N_KV * (SEQ / 32) * 4, 64, 0, stream>>>(Qbf, Kbf, Vtbf, AOut);
  gemm_bt_k<1><<<(ROWS / 128) * (HIDDEN_DIM / 128), 256, 0, stream>>>(AOut, Wobf, (void*)out,
                                                                      ROWS, HIDDEN_DIM, HIDDEN_DIM);
}

// Round 5
// 558.308 us; speedup vs baseline: 1.2528x; 1.2528x over previous
//
#include <hip/hip_runtime.h>
#include <stdint.h>

#define N_HEADS   32
#define N_KV      8
#define HEAD_DIM  128
#define HIDDEN_DIM 4096
#define BSZ       2
#define SEQ       2048
#define TOT_HEADS 48
#define QKV_DIM   6144   // TOT_HEADS * HEAD_DIM
#define ROWS      4096   // BSZ * SEQ
#define ROPE_HEADS 40    // Q + K heads (V not rope'd)

typedef __attribute__((ext_vector_type(4)))  float f32x4;
typedef __attribute__((ext_vector_type(16))) float f32x16;
typedef __attribute__((ext_vector_type(8)))  short bf16x8;
typedef unsigned short u16;
typedef unsigned int   u32;

#define AS1 __attribute__((address_space(1)))
#define AS3 __attribute__((address_space(3)))

static __device__ __forceinline__ float bf16f(u16 u) { return __uint_as_float(((u32)u) << 16); }
static __device__ __forceinline__ u16 f2bf(float f) {
  u32 x = __float_as_uint(f);
  x += 0x7fffu + ((x >> 16) & 1u);   // round-to-nearest-even
  return (u16)(x >> 16);
}
static __device__ __forceinline__ u32 cvt_pk_bf16(float lo, float hi) {
  u32 r;
  asm("v_cvt_pk_bf16_f32 %0, %1, %2" : "=v"(r) : "v"(lo), "v"(hi));
  return r;
}
static __device__ __forceinline__ bf16x8 mk8(u32 a, u32 b, u32 c, u32 d) {
  union { u32 u[4]; bf16x8 v; } x;
  x.u[0] = a; x.u[1] = b; x.u[2] = c; x.u[3] = d;
  return x.v;
}

// ---------------- cast f32 -> bf16 (vectorized) ----------------
__global__ void cast_f32_bf16_k(const float4* __restrict__ in, ushort4* __restrict__ out, int n4) {
  int i = blockIdx.x * blockDim.x + threadIdx.x;
  const int stride = gridDim.x * blockDim.x;
  for (; i < n4; i += stride) {
    float4 v = in[i];
    ushort4 o;
    o.x = f2bf(v.x); o.y = f2bf(v.y); o.z = f2bf(v.z); o.w = f2bf(v.w);
    out[i] = o;
  }
}

// ---------------- RoPE cos/sin tables (S x 64, half-dim) ----------------
__global__ void rope_tables_k(float* __restrict__ ctab, float* __restrict__ stab) {
  int t = blockIdx.x * blockDim.x + threadIdx.x;
  if (t >= SEQ * 64) return;
  int s = t >> 6, i = t & 63;
  float inv = powf(10000.0f, -(float)i / 64.0f);
  float ang = (float)s * inv;
  float sv, cv;
  sincosf(ang, &sv, &cv);
  ctab[t] = cv; stab[t] = sv;
}

// ---------------- bf16 GEMM: C[M,N] = A[M,K] * B[N,K]^T ----------------
// 128x128 tile, BK=64, 4 waves (2x2), each wave 64x64 via 4x4 mfma_16x16x32 frags.
// LDS logical layout: slot(row, cs) holds global chunk c = cs ^ (row&7).
// Staging via global_load_lds (linear LDS dest, swizzle pre-applied to per-lane
// GLOBAL source address — same involution as the swizzled ds_read).
template<int F32OUT>
__global__ __launch_bounds__(256, 2)
void gemm_bt_k(const u16* __restrict__ A, const u16* __restrict__ Bw,
               void* __restrict__ C, int M, int N, int K)
{
  __shared__ uint4 smA[1024];
  __shared__ uint4 smB[1024];
  const int tid = threadIdx.x;
  const int nbx = N >> 7;
  const int bm = (blockIdx.x / nbx) << 7;
  const int bn = (blockIdx.x % nbx) << 7;
  const int lane = tid & 63;
  const int wave = tid >> 6;
  const int wm = (wave >> 1) << 6;
  const int wn = (wave & 1) << 6;
  const int fr = lane & 15;   // fragment row/col within 16
  const int fq = lane >> 4;   // 0..3

  f32x4 acc[4][4];
#pragma unroll
  for (int i = 0; i < 4; ++i)
#pragma unroll
    for (int j = 0; j < 4; ++j)
      acc[i][j] = {0.f, 0.f, 0.f, 0.f};

  const int gl_r = lane >> 3;                  // row-within-8 for this lane
  const int gl_c = (lane & 7) ^ gl_r;          // pre-swizzled global chunk

  for (int k0 = 0; k0 < K; k0 += 64) {
#pragma unroll
    for (int i = 0; i < 4; ++i) {
      const int rbase = (wave << 5) + (i << 3);      // wave-uniform row base
      const int row = rbase + gl_r;
      const u16* gA = A  + (size_t)(bm + row) * K + k0 + (gl_c << 3);
      const u16* gB = Bw + (size_t)(bn + row) * K + k0 + (gl_c << 3);
      __builtin_amdgcn_global_load_lds((const AS1 u32*)gA, (AS3 u32*)&smA[rbase << 3], 16, 0, 0);
      __builtin_amdgcn_global_load_lds((const AS1 u32*)gB, (AS3 u32*)&smB[rbase << 3], 16, 0, 0);
    }
    __syncthreads();
#pragma unroll
    for (int kk = 0; kk < 2; ++kk) {
      bf16x8 af[4], bfr[4];
      const int cc = (kk << 2) + fq;
#pragma unroll
      for (int m = 0; m < 4; ++m) {
        const int row = wm + (m << 4) + fr;
        af[m] = *reinterpret_cast<const bf16x8*>(&smA[(row << 3) + (cc ^ (row & 7))]);
      }
#pragma unroll
      for (int n = 0; n < 4; ++n) {
        const int row = wn + (n << 4) + fr;
        bfr[n] = *reinterpret_cast<const bf16x8*>(&smB[(row << 3) + (cc ^ (row & 7))]);
      }
#pragma unroll
      for (int m = 0; m < 4; ++m)
#pragma unroll
        for (int n = 0; n < 4; ++n)
          acc[m][n] = __builtin_amdgcn_mfma_f32_16x16x32_bf16(af[m], bfr[n], acc[m][n], 0, 0, 0);
    }
    __syncthreads();
  }

  // epilogue: D[row][col], row = fq*4+i (+m*16), col = fr (+n*16)
  const int col0 = bn + wn + fr;
#pragma unroll
  for (int m = 0; m < 4; ++m) {
#pragma unroll
    for (int i = 0; i < 4; ++i) {
      const int row = bm + wm + (m << 4) + (fq << 2) + i;
      if (F32OUT) {
        float* rp = reinterpret_cast<float*>(C) + (size_t)row * N + col0;
#pragma unroll
        for (int n = 0; n < 4; ++n) rp[n << 4] = acc[m][n][i];
      } else {
        u16* rp = reinterpret_cast<u16*>(C) + (size_t)row * N + col0;
#pragma unroll
        for (int n = 0; n < 4; ++n) rp[n << 4] = f2bf(acc[m][n][i]);
      }
    }
  }
}

// ---------------- RoPE + scatter Q,K heads -> Q(B,H,S,D) K(B,KV,S,D) ----------------
// Q heads are pre-scaled by 1/sqrt(128)*log2(e) so attention scores come out of
// the QK^T MFMA already in log2 domain.
__global__ void rope_scatter_k(const u16* __restrict__ QKV,
                               const float* __restrict__ ctab, const float* __restrict__ stab,
                               u16* __restrict__ Qo, u16* __restrict__ Ko)
{
  const int t = blockIdx.x * blockDim.x + threadIdx.x;  // ROWS*40*64 threads
  const int d = t & 63;
  const int hh = (t >> 6) % ROPE_HEADS;
  const int row = t / (64 * ROPE_HEADS);
  const int b = row >> 11, sq = row & (SEQ - 1);
  const u16* src = QKV + (size_t)row * QKV_DIM + hh * HEAD_DIM;
  const float x1 = bf16f(src[d]);
  const float x2 = bf16f(src[d + 64]);
  const float c = ctab[(sq << 6) + d], sn = stab[(sq << 6) + d];
  float y1 = x1 * c - x2 * sn;
  float y2 = x2 * c + x1 * sn;
  u16* dst;
  if (hh < N_HEADS) {
    const float SC2 = 0.1275170747f;   // (1/sqrt(128)) * log2(e)
    y1 *= SC2; y2 *= SC2;
    dst = Qo + ((size_t)(b * N_HEADS + hh) * SEQ + sq) * HEAD_DIM;
  } else {
    dst = Ko + ((size_t)(b * N_KV + (hh - N_HEADS)) * SEQ + sq) * HEAD_DIM;
  }
  dst[d] = f2bf(y1);
  dst[d + 64] = f2bf(y2);
}

// ---------------- V transpose: QKV cols [5120,6144) -> Vt[b][kv][d][s] ----------------
// 64x64 u16 tile = 4096 elems; 256 threads x 8 elems => TWO passes each phase.
__global__ __launch_bounds__(256)
void vtrans_k(const u16* __restrict__ QKV, u16* __restrict__ Vt)
{
  __shared__ u16 tile[64][72];
  const int idx = blockIdx.x;           // dt(1) | st(5) | kv(3) | b(1)
  const int dt = idx & 1;
  const int st = (idx >> 1) & 31;
  const int kv = (idx >> 6) & 7;
  const int b  = idx >> 9;
  const int tid = threadIdx.x;
  const int s0 = st << 6, d0 = dt << 6;
  const int rl = tid >> 3, cc8 = (tid & 7) << 3;
#pragma unroll
  for (int p = 0; p < 2; ++p) {
    const int sl = rl + (p << 5);
    const u16* src = QKV + (size_t)(b * SEQ + s0 + sl) * QKV_DIM
                   + (N_HEADS + N_KV + kv) * HEAD_DIM + d0 + cc8;
    *reinterpret_cast<uint4*>(&tile[sl][cc8]) = *reinterpret_cast<const uint4*>(src);
  }
  __syncthreads();
#pragma unroll
  for (int p = 0; p < 2; ++p) {
    const int dl = rl + (p << 5);
    u16 tmp[8];
#pragma unroll
    for (int k2 = 0; k2 < 8; ++k2) tmp[k2] = tile[cc8 + k2][dl];
    u16* dst = Vt + ((size_t)(b * N_KV + kv) * HEAD_DIM + d0 + dl) * SEQ + s0 + cc8;
    *reinterpret_cast<uint4*>(dst) = *reinterpret_cast<const uint4*>(tmp);
  }
}

// ---------------- MFMA flash attention (causal GQA, LDS-shared K/V) ----------------
// Block = 4 waves = the 4 GQA heads sharing one KV head; q-tile of 32 rows.
// Per 32-key subtile: K (32x128, 8KB) and Vt (128x32, 8KB) staged ONCE per block
// into double-buffered LDS via global_load_lds (coalesced 1KB/instr), prefetched:
// {barrier; stage(s+1); compute(s)} — stage latency hides under compute.
// LDS content XOR-swizzled via pre-swizzled GLOBAL source (rule #21): K slot
// (row, cs) holds chunk cs^(row&15); V slot (d, cs) holds chunk cs^(d&3).
// Load balance: block runs q-tile pair (32+p, 31-p) => exactly 65 subtiles each.
// Swapped QK^T: T = mfma(K, Q) -> lane holds scores of q-row (lane&31).
// PV output D-rows are q = (r&3)+8*(r>>2)+4*(lane>>5): stats redistributed
// per-register via __shfl when applied to O.
__global__ __launch_bounds__(256, 2)
void attn_mfma_k(const u16* __restrict__ Q, const u16* __restrict__ K,
                 const u16* __restrict__ Vt, u16* __restrict__ Out)
{
  __shared__ uint4 Ksm[2][512];
  __shared__ uint4 Vsm[2][512];
  const int tid  = threadIdx.x;
  const int lane = tid & 63;
  const int w    = tid >> 6;
  const int idx  = blockIdx.x;                    // p(5) | b(1) | kvh(3)
  const int kvh  = idx & 7;                       // XCD-pinned KV
  const int b    = (idx >> 3) & 1;
  const int p    = idx >> 4;                      // 0..31
  const int h    = (kvh << 2) + w;

  const int ql = lane & 31;
  const int hh = lane >> 5;

  const u16* Qh = Q  + (size_t)(b * N_HEADS + h) * SEQ * HEAD_DIM;
  const u16* Kb = K  + (size_t)(b * N_KV + kvh) * SEQ * HEAD_DIM;
  const u16* Vb = Vt + (size_t)(b * N_KV + kvh) * HEAD_DIM * SEQ;

  // loop-invariant swizzled read offsets
  int koff[8];
#pragma unroll
  for (int f = 0; f < 8; ++f) koff[f] = (ql << 4) + (((f << 1) + hh) ^ (ql & 15));
  int voff0[4], voff1[4];
#pragma unroll
  for (int dblk = 0; dblk < 4; ++dblk) {
    const int d = (dblk << 5) + ql;
    voff0[dblk] = (d << 2) + (hh ^ (d & 3));
    voff1[dblk] = (d << 2) + ((2 + hh) ^ (d & 3));
  }

  auto stage = [&](int buf, int ks) {
#pragma unroll
    for (int i = 0; i < 2; ++i) {
      const int base = i * 256 + w * 64;           // wave-uniform LDS chunk base
      const int sl = base + lane;
      const int row = sl >> 4, cs = sl & 15;
      const int g = cs ^ (row & 15);
      const u16* src = Kb + (size_t)(ks + row) * HEAD_DIM + (g << 3);
      __builtin_amdgcn_global_load_lds((const AS1 u32*)src, (AS3 u32*)&Ksm[buf][base], 16, 0, 0);
    }
#pragma unroll
    for (int i = 0; i < 2; ++i) {
      const int base = i * 256 + w * 64;
      const int sl = base + lane;
      const int d = sl >> 2, cs = sl & 3;
      const int g = cs ^ (d & 3);
      const u16* src = Vb + (size_t)d * SEQ + ks + (g << 3);
      __builtin_amdgcn_global_load_lds((const AS1 u32*)src, (AS3 u32*)&Vsm[buf][base], 16, 0, 0);
    }
  };

#pragma unroll 1
  for (int pass = 0; pass < 2; ++pass) {
    const int qi = pass ? (31 - p) : (32 + p);
    const int q0 = qi << 5;

    // Q B-frags: lane holds Q[q0+ql][16f + 8hh + j]  (already log2-scaled)
    bf16x8 qf[8];
#pragma unroll
    for (int f = 0; f < 8; ++f)
      qf[f] = *reinterpret_cast<const bf16x8*>(Qh + (size_t)(q0 + ql) * HEAD_DIM + 16 * f + 8 * hh);

    f32x16 o[4];
#pragma unroll
    for (int dblk = 0; dblk < 4; ++dblk)
#pragma unroll
      for (int r = 0; r < 16; ++r) o[dblk][r] = 0.f;
    float m2 = -1e30f, lsum = 0.f;

    __syncthreads();          // protect buf0 from prev pass's readers
    stage(0, 0);

#pragma unroll 1
    for (int s = 0; s <= qi; ++s) {
      const int cur = s & 1;
      __syncthreads();        // drains stage(s); prev compute done
      if (s < qi) stage(cur ^ 1, (s + 1) << 5);   // prefetch flies under compute

      // ---- QK^T from LDS ----
      f32x16 T;
#pragma unroll
      for (int r = 0; r < 16; ++r) T[r] = 0.f;
      __builtin_amdgcn_s_setprio(1);
#pragma unroll
      for (int f = 0; f < 8; ++f) {
        const bf16x8 kf = *reinterpret_cast<const bf16x8*>(&Ksm[cur][koff[f]]);
        T = __builtin_amdgcn_mfma_f32_32x32x16_bf16(kf, qf[f], T, 0, 0, 0);
      }
      __builtin_amdgcn_s_setprio(0);

      // ---- causal mask (tail subtile only) + tile max ----
      if (s == qi) {
#pragma unroll
        for (int r = 0; r < 16; ++r) {
          const int krow = (r & 3) + ((r >> 2) << 3) + (hh << 2);
          if (krow > ql) T[r] = -1e30f;
        }
      }
      float mt = T[0];
#pragma unroll
      for (int r = 1; r < 16; ++r) mt = fmaxf(mt, T[r]);
      mt = fmaxf(mt, __shfl_xor(mt, 32));

      // ---- defer-max rescale (THR = 8 in log2 domain) ----
      if (__any(mt > m2 + 8.f)) {
        const float mnew = fmaxf(m2, mt);
        const float resc = exp2f(m2 - mnew);
        lsum *= resc;
#pragma unroll
        for (int r = 0; r < 16; ++r) {
          const int qr = (r & 3) + ((r >> 2) << 3) + (hh << 2);
          const float rr = __shfl(resc, qr);
#pragma unroll
          for (int dblk = 0; dblk < 4; ++dblk) o[dblk][r] *= rr;
        }
        m2 = mnew;
      }

      // ---- exp2 + row sum ----
      float ps = 0.f;
#pragma unroll
      for (int r = 0; r < 16; ++r) { const float pv = exp2f(T[r] - m2); T[r] = pv; ps += pv; }
      ps += __shfl_xor(ps, 32);
      lsum += ps;

      // ---- pack P -> bf16 A-frags (cvt_pk + half-swap) ----
      u32 pk[8], sw[8];
#pragma unroll
      for (int i = 0; i < 8; ++i) {
        pk[i] = cvt_pk_bf16(T[2 * i], T[2 * i + 1]);
        sw[i] = (u32)__shfl_xor((int)pk[i], 32);
      }
      const bf16x8 a0 = hh ? mk8(sw[2], sw[3], pk[2], pk[3])
                           : mk8(pk[0], pk[1], sw[0], sw[1]);
      const bf16x8 a1 = hh ? mk8(sw[6], sw[7], pk[6], pk[7])
                           : mk8(pk[4], pk[5], sw[4], sw[5]);

      // ---- PV from LDS ----
      __builtin_amdgcn_s_setprio(1);
#pragma unroll
      for (int dblk = 0; dblk < 4; ++dblk) {
        const bf16x8 va = *reinterpret_cast<const bf16x8*>(&Vsm[cur][voff0[dblk]]);
        o[dblk] = __builtin_amdgcn_mfma_f32_32x32x16_bf16(a0, va, o[dblk], 0, 0, 0);
        const bf16x8 vb2 = *reinterpret_cast<const bf16x8*>(&Vsm[cur][voff1[dblk]]);
        o[dblk] = __builtin_amdgcn_mfma_f32_32x32x16_bf16(a1, vb2, o[dblk], 0, 0, 0);
      }
      __builtin_amdgcn_s_setprio(0);
    }

    // ---- write out: row q0+qr, col h*128 + dblk*32 + ql; normalize lsum[qr] ----
    u16* Ob = Out + (size_t)(b * SEQ + q0) * HIDDEN_DIM + h * HEAD_DIM + ql;
#pragma unroll
    for (int r = 0; r < 16; ++r) {
      const int qr = (r & 3) + ((r >> 2) << 3) + (hh << 2);
      const float il = 1.0f / __shfl(lsum, qr);
      u16* rp = Ob + (size_t)qr * HIDDEN_DIM;
#pragma unroll
      for (int dblk = 0; dblk < 4; ++dblk)
        rp[dblk * 32] = f2bf(o[dblk][r] * il);
    }
  }
}

// ---------------- launch ----------------
extern "C" void kernel_launch(void* const* d_in, const int* in_sizes, int n_in,
                              void* d_out, int out_size, void* d_ws, size_t ws_size,
                              hipStream_t stream)
{
  const float* hs   = (const float*)d_in[0];
  const float* wqkv = (const float*)d_in[1];
  const float* wo   = (const float*)d_in[2];
  float* out = (float*)d_out;
  char* ws = (char*)d_ws;
  size_t off = 0;
  auto alloc = [&](size_t bytes) -> void* {
    void* p = ws + off;
    off += (bytes + 255) & ~(size_t)255;
    return p;
  };
  u16* Xbf    = (u16*)alloc((size_t)ROWS * HIDDEN_DIM * 2);
  u16* Wqkvbf = (u16*)alloc((size_t)QKV_DIM * HIDDEN_DIM * 2);
  u16* Wobf   = (u16*)alloc((size_t)HIDDEN_DIM * HIDDEN_DIM * 2);
  u16* QKVbf  = (u16*)alloc((size_t)ROWS * QKV_DIM * 2);
  u16* Qbf    = (u16*)alloc((size_t)BSZ * N_HEADS * SEQ * HEAD_DIM * 2);
  u16* Kbf    = (u16*)alloc((size_t)BSZ * N_KV * SEQ * HEAD_DIM * 2);
  u16* Vtbf   = (u16*)alloc((size_t)BSZ * N_KV * SEQ * HEAD_DIM * 2);
  float* ctab = (float*)alloc((size_t)SEQ * 64 * 4);
  float* stab = (float*)alloc((size_t)SEQ * 64 * 4);
  u16* AOut   = (u16*)alloc((size_t)ROWS * HIDDEN_DIM * 2);
  if (off > ws_size) return;

  cast_f32_bf16_k<<<2048, 256, 0, stream>>>((const float4*)hs,   (ushort4*)Xbf,    ROWS * HIDDEN_DIM / 4);
  cast_f32_bf16_k<<<2048, 256, 0, stream>>>((const float4*)wqkv, (ushort4*)Wqkvbf, QKV_DIM * HIDDEN_DIM / 4);
  cast_f32_bf16_k<<<2048, 256, 0, stream>>>((const float4*)wo,   (ushort4*)Wobf,   HIDDEN_DIM * HIDDEN_DIM / 4);
  rope_tables_k<<<(SEQ * 64) / 256, 256, 0, stream>>>(ctab, stab);

  gemm_bt_k<0><<<(ROWS / 128) * (QKV_DIM / 128), 256, 0, stream>>>(Xbf, Wqkvbf, (void*)QKVbf,
                                                                   ROWS, QKV_DIM, HIDDEN_DIM);
  rope_scatter_k<<<ROWS * ROPE_HEADS * 64 / 256, 256, 0, stream>>>(QKVbf, ctab, stab, Qbf, Kbf);
  vtrans_k<<<BSZ * N_KV * (SEQ / 64) * (HEAD_DIM / 64), 256, 0, stream>>>(QKVbf, Vtbf);
  attn_mfma_k<<<BSZ * N_KV * 32, 256, 0, stream>>>(Qbf, Kbf, Vtbf, AOut);
  gemm_bt_k<1><<<(ROWS / 128) * (HIDDEN_DIM / 128), 256, 0, stream>>>(AOut, Wobf, (void*)out,
                                                                      ROWS, HIDDEN_DIM, HIDDEN_DIM);
}